// Round 9
// baseline (117574.280 us; speedup 1.0000x reference)
//
#include <hip/hip_runtime.h>
#include <hip/hip_fp16.h>
#include <stdint.h>

typedef unsigned short ushort_t;
typedef unsigned int uint_t;
typedef unsigned long long ull_t;

#define TSTEPS 512
#define PSTEPS 64     // steps for additive probes
#define P0STEPS 256   // steps for barrier-only probe (lifted into top-5 if costly)
#define BATCH  64
#define ISZ    512
#define HSZ    1024
#define GSZ    4096
#define NB     256
#define NT     256
#define PITCH  1032
#define SLAB   (16 * PITCH)

static constexpr size_t OFF_XPREV = (size_t)TSTEPS * BATCH * HSZ;
static constexpr size_t OFF_H     = OFF_XPREV + (size_t)BATCH * 1024;
static constexpr size_t OFF_HP    = OFF_H  + (size_t)BATCH * HSZ;
static constexpr size_t OFF_C     = OFF_HP + (size_t)BATCH * HSZ;
static constexpr size_t OFF_M     = OFF_C  + (size_t)BATCH * HSZ;
static constexpr size_t OFF_REG   = OFF_M  + (size_t)BATCH * GSZ;

#define TH_RAW 0.1f
#define TH_QNT 0.1015625f

__device__ __forceinline__ float qA(float x) {
  float v = rintf(x * 256.0f);
  v = fminf(fmaxf(v, -32768.0f), 32767.0f);
  return v * 0.00390625f;
}
__device__ __forceinline__ float qN(float x) {
  float v = rintf(x * 256.0f);
  v = fminf(fmaxf(v, -512.0f), 511.0f);
  return v * 0.00390625f;
}
__device__ __forceinline__ float sigm(float x) { return 1.0f / (1.0f + expf(-x)); }

// ---------------------------------------------------------------------------
__global__ __launch_bounds__(256) void xscan_kernel(const float* __restrict__ x,
                                                    float* __restrict__ dx,
                                                    float* __restrict__ out_xprev) {
  const int gid = blockIdx.x * blockDim.x + threadIdx.x;
  float xp = 0.0f;
  #pragma unroll 8
  for (int t = 0; t < TSTEPS; t++) {
    float xq = qA(x[(size_t)t * (BATCH * ISZ) + gid]);
    float d  = xq - xp;
    float da = fabsf(d);
    dx[(size_t)t * (BATCH * ISZ) + gid] = (da < TH_QNT) ? 0.0f : d;
    if (da >= TH_RAW) xp = xq;
  }
  const int b = gid >> 9;
  const int i = gid & 511;
  out_xprev[(size_t)b * 1024 + i]       = xp;
  out_xprev[(size_t)b * 1024 + 512 + i] = 0.0f;
}

// ---------------------------------------------------------------------------
// Grid barrier (validated r7/r8 semantics): vmcnt drain -> RELAXED flag store;
// wave 0 polls via paired u64 relaxed agent loads. No release/acquire.
// ---------------------------------------------------------------------------
__device__ __forceinline__ void gbar(int* flags, int e) {
  asm volatile("s_waitcnt vmcnt(0)" ::: "memory");
  __syncthreads();
  if (threadIdx.x == 0) {
    __hip_atomic_store(&flags[blockIdx.x], e, __ATOMIC_RELAXED, __HIP_MEMORY_SCOPE_AGENT);
  }
  if (threadIdx.x < 64) {
    const ull_t* f64 = (const ull_t*)flags;
    const int l = threadIdx.x;
    bool done;
    do {
      ull_t a = __hip_atomic_load(f64 + l,      __ATOMIC_RELAXED, __HIP_MEMORY_SCOPE_AGENT);
      ull_t c = __hip_atomic_load(f64 + 64 + l, __ATOMIC_RELAXED, __HIP_MEMORY_SCOPE_AGENT);
      bool ok = ((int)a >= e) & ((int)(a >> 32) >= e) &
                ((int)c >= e) & ((int)(c >> 32) >= e);
      done = __all(ok);
      if (!done) __builtin_amdgcn_s_sleep(2);
    } while (!done);
  }
  __syncthreads();
}

// ---------------------------------------------------------------------------
// ABLATION PROBE: same structure as scan_kernel, phases compile-time gated.
// MODE bits: 1=stage dh->LDS, 2=x-dot, 4=h-dot(LDS), 8=gates+out+dh-store.
// Barrier always on. DCE guards: u64 sink XOR on staged data, volatile LDS
// guard read, final dummy store of all live state (rule #17).
// ---------------------------------------------------------------------------
template <int MODE, int STEPS>
__global__ __launch_bounds__(NT, 1) void probe_kernel(
    const float* __restrict__ dx, const float* __restrict__ w_ih,
    const float* __restrict__ w_hh, const float* __restrict__ b_ih,
    const float* __restrict__ b_hh, float* __restrict__ dummy,
    __half* __restrict__ dh16, int* flags) {
  __shared__ __align__(16) __half dhs[4 * SLAB];

  const int tid  = threadIdx.x;
  const int wid  = tid >> 6;
  const int lane = tid & 63;
  const int jj   = tid & 3;
  const int b    = tid >> 2;
  const int lb   = b & 15;
  const int j    = blockIdx.x * 4 + jj;
  const int g0 = j, g1 = j + HSZ, g2 = j + 2 * HSZ, g3 = j + 3 * HSZ;
  const size_t DHBUF = (size_t)BATCH * HSZ;

  float m0 = b_ih[g0] + b_hh[g0];
  float m1 = b_ih[g1] + b_hh[g1];
  float m2 = b_ih[g2] + b_hh[g2];
  float m3 = b_ih[g3] + b_hh[g3];
  float c = 0.0f, hp = 0.0f, h = 0.0f, regacc = 0.0f;
  ull_t sink = 0;

  const float4* __restrict__ wi0 = (const float4*)(w_ih + (size_t)g0 * ISZ);
  const float4* __restrict__ wi1 = (const float4*)(w_ih + (size_t)g1 * ISZ);
  const float4* __restrict__ wi2 = (const float4*)(w_ih + (size_t)g2 * ISZ);
  const float4* __restrict__ wi3 = (const float4*)(w_ih + (size_t)g3 * ISZ);
  const float4* __restrict__ wh0 = (const float4*)(w_hh + (size_t)g0 * HSZ);
  const float4* __restrict__ wh1 = (const float4*)(w_hh + (size_t)g1 * HSZ);
  const float4* __restrict__ wh2 = (const float4*)(w_hh + (size_t)g2 * HSZ);
  const float4* __restrict__ wh3 = (const float4*)(w_hh + (size_t)g3 * HSZ);

  __half* slab = dhs + wid * SLAB;
  const __half* lrow = slab + lb * PITCH;
  int epoch = 1;

  for (int t = 0; t < STEPS; t++) {
    if constexpr (MODE & 1) {  // ---- stage dh -> LDS (coalesced agent loads)
      const ull_t* __restrict__ src =
          (const ull_t*)(dh16 + (size_t)(t & 1) * DHBUF) + (size_t)wid * 4096;
      #pragma unroll
      for (int r4 = 0; r4 < 16; r4 += 4) {
        ull_t v[16];
        #pragma unroll
        for (int rr = 0; rr < 4; ++rr)
          #pragma unroll
          for (int i = 0; i < 4; ++i)
            v[rr * 4 + i] = __hip_atomic_load(src + (r4 + rr) * 256 + i * 64 + lane,
                                              __ATOMIC_RELAXED, __HIP_MEMORY_SCOPE_AGENT);
        #pragma unroll
        for (int rr = 0; rr < 4; ++rr)
          #pragma unroll
          for (int i = 0; i < 4; ++i) {
            sink ^= v[rr * 4 + i];
            *(ull_t*)(slab + (r4 + rr) * PITCH + (i * 64 + lane) * 4) = v[rr * 4 + i];
          }
      }
      // volatile LDS guard read keeps ds_writes live even when h-dot is off
      if (__half2float(((volatile __half*)lrow)[0]) == 12345.0f) dummy[0] = 1.0f;
    }

    float a0 = 0.f, a1 = 0.f, a2 = 0.f, a3 = 0.f;
    if constexpr (MODE & 2) {  // ---- x-dot (cached loads)
      const float4* __restrict__ xr = (const float4*)(dx + ((size_t)t * BATCH + b) * ISZ);
      #pragma unroll 8
      for (int k = 0; k < ISZ / 4; k++) {
        float4 xv = xr[k]; float4 wv;
        wv = wi0[k]; a0 = fmaf(xv.x, wv.x, fmaf(xv.y, wv.y, fmaf(xv.z, wv.z, fmaf(xv.w, wv.w, a0))));
        wv = wi1[k]; a1 = fmaf(xv.x, wv.x, fmaf(xv.y, wv.y, fmaf(xv.z, wv.z, fmaf(xv.w, wv.w, a1))));
        wv = wi2[k]; a2 = fmaf(xv.x, wv.x, fmaf(xv.y, wv.y, fmaf(xv.z, wv.z, fmaf(xv.w, wv.w, a2))));
        wv = wi3[k]; a3 = fmaf(xv.x, wv.x, fmaf(xv.y, wv.y, fmaf(xv.z, wv.z, fmaf(xv.w, wv.w, a3))));
      }
    }
    if constexpr (MODE & 4) {  // ---- h-dot (LDS reads + cached weight loads)
      #pragma unroll 4
      for (int i = 0; i < 128; ++i) {
        uint4 u = *(const uint4*)(lrow + i * 8);
        float h0 = __half2float(__ushort_as_half((ushort_t)(u.x & 0xffff)));
        float h1 = __half2float(__ushort_as_half((ushort_t)(u.x >> 16)));
        float h2 = __half2float(__ushort_as_half((ushort_t)(u.y & 0xffff)));
        float h3 = __half2float(__ushort_as_half((ushort_t)(u.y >> 16)));
        float h4 = __half2float(__ushort_as_half((ushort_t)(u.z & 0xffff)));
        float h5 = __half2float(__ushort_as_half((ushort_t)(u.z >> 16)));
        float h6 = __half2float(__ushort_as_half((ushort_t)(u.w & 0xffff)));
        float h7 = __half2float(__ushort_as_half((ushort_t)(u.w >> 16)));
        const int wi = i * 2;
        float4 w;
        w = wh0[wi];     a0 = fmaf(h0, w.x, fmaf(h1, w.y, fmaf(h2, w.z, fmaf(h3, w.w, a0))));
        w = wh0[wi + 1]; a0 = fmaf(h4, w.x, fmaf(h5, w.y, fmaf(h6, w.z, fmaf(h7, w.w, a0))));
        w = wh1[wi];     a1 = fmaf(h0, w.x, fmaf(h1, w.y, fmaf(h2, w.z, fmaf(h3, w.w, a1))));
        w = wh1[wi + 1]; a1 = fmaf(h4, w.x, fmaf(h5, w.y, fmaf(h6, w.z, fmaf(h7, w.w, a1))));
        w = wh2[wi];     a2 = fmaf(h0, w.x, fmaf(h1, w.y, fmaf(h2, w.z, fmaf(h3, w.w, a2))));
        w = wh2[wi + 1]; a2 = fmaf(h4, w.x, fmaf(h5, w.y, fmaf(h6, w.z, fmaf(h7, w.w, a2))));
        w = wh3[wi];     a3 = fmaf(h0, w.x, fmaf(h1, w.y, fmaf(h2, w.z, fmaf(h3, w.w, a3))));
        w = wh3[wi + 1]; a3 = fmaf(h4, w.x, fmaf(h5, w.y, fmaf(h6, w.z, fmaf(h7, w.w, a3))));
      }
    }
    m0 += a0; m1 += a1; m2 += a2; m3 += a3;

    if constexpr (MODE & 8) {  // ---- gates + h write + dh produce/store
      float pi = qA(m0), pf = qA(m1), pg = qA(m2), po = qA(m3);
      float gi = qN(sigm(pi));
      float gf = qN(sigm(pf));
      float gg = qN(tanhf(pg));
      float go = qN(sigm(po));
      float cn = c * gf + gi * gg;
      c = qA(cn);
      float ct = qN(tanhf(c));
      h = qA(go * ct);
      dummy[(size_t)b * HSZ + j] = h;
      if (t < STEPS - 1) {
        float d  = h - hp;
        float da = fabsf(d);
        float dm = (da < TH_QNT) ? 0.0f : d;
        if (da >= TH_RAW) hp = h;
        regacc += fabsf(dm);
        ushort_t my = __half_as_ushort(__float2half(dm));
        ushort_t other = (ushort_t)__shfl((int)my, tid ^ 1, 64);
        if ((tid & 1) == 0) {
          uint_t dw = (uint_t)my | ((uint_t)other << 16);
          uint_t* dhw = (uint_t*)(dh16 + (size_t)((t + 1) & 1) * DHBUF);
          __hip_atomic_store(&dhw[((size_t)b * HSZ + j) >> 1], dw,
                             __ATOMIC_RELAXED, __HIP_MEMORY_SCOPE_AGENT);
        }
      }
    }
    gbar(flags, epoch); epoch++;
  }
  // live-state sink (prevents DCE of every gated phase)
  dummy[(size_t)blockIdx.x * NT + tid] =
      m0 + m1 + m2 + m3 + h + hp + c + regacc + (float)(uint_t)(sink & 0xff);
}

// ---------------------------------------------------------------------------
// REAL kernel: byte-identical to round 8 (validated, absmax 0.1171875).
// ---------------------------------------------------------------------------
__global__ __launch_bounds__(NT, 1) void scan_kernel(
    const float* __restrict__ dx, const float* __restrict__ w_ih,
    const float* __restrict__ w_hh, const float* __restrict__ b_ih,
    const float* __restrict__ b_hh, float* __restrict__ out,
    __half* __restrict__ dh16, float* __restrict__ partials, int* flags) {
  __shared__ __align__(16) __half dhs[4 * SLAB];
  __shared__ float red[NT];

  const int tid  = threadIdx.x;
  const int wid  = tid >> 6;
  const int lane = tid & 63;
  const int jj   = tid & 3;
  const int b    = tid >> 2;
  const int lb   = b & 15;
  const int j    = blockIdx.x * 4 + jj;
  const int g0 = j, g1 = j + HSZ, g2 = j + 2 * HSZ, g3 = j + 3 * HSZ;
  const size_t DHBUF = (size_t)BATCH * HSZ;

  float m0 = b_ih[g0] + b_hh[g0];
  float m1 = b_ih[g1] + b_hh[g1];
  float m2 = b_ih[g2] + b_hh[g2];
  float m3 = b_ih[g3] + b_hh[g3];
  float c = 0.0f, hp = 0.0f, h = 0.0f, regacc = 0.0f;

  const float4* __restrict__ wi0 = (const float4*)(w_ih + (size_t)g0 * ISZ);
  const float4* __restrict__ wi1 = (const float4*)(w_ih + (size_t)g1 * ISZ);
  const float4* __restrict__ wi2 = (const float4*)(w_ih + (size_t)g2 * ISZ);
  const float4* __restrict__ wi3 = (const float4*)(w_ih + (size_t)g3 * ISZ);
  const float4* __restrict__ wh0 = (const float4*)(w_hh + (size_t)g0 * HSZ);
  const float4* __restrict__ wh1 = (const float4*)(w_hh + (size_t)g1 * HSZ);
  const float4* __restrict__ wh2 = (const float4*)(w_hh + (size_t)g2 * HSZ);
  const float4* __restrict__ wh3 = (const float4*)(w_hh + (size_t)g3 * HSZ);

  __half* slab = dhs + wid * SLAB;
  const __half* lrow = slab + lb * PITCH;
  int epoch = 1;

  for (int t = 0; t < TSTEPS; t++) {
    const ull_t* __restrict__ src =
        (const ull_t*)(dh16 + (size_t)(t & 1) * DHBUF) + (size_t)wid * 4096;
    #pragma unroll
    for (int r4 = 0; r4 < 16; r4 += 4) {
      ull_t v[16];
      #pragma unroll
      for (int rr = 0; rr < 4; ++rr)
        #pragma unroll
        for (int i = 0; i < 4; ++i)
          v[rr * 4 + i] = __hip_atomic_load(src + (r4 + rr) * 256 + i * 64 + lane,
                                            __ATOMIC_RELAXED, __HIP_MEMORY_SCOPE_AGENT);
      #pragma unroll
      for (int rr = 0; rr < 4; ++rr)
        #pragma unroll
        for (int i = 0; i < 4; ++i)
          *(ull_t*)(slab + (r4 + rr) * PITCH + (i * 64 + lane) * 4) = v[rr * 4 + i];
    }

    float a0 = 0.f, a1 = 0.f, a2 = 0.f, a3 = 0.f;
    {
      const float4* __restrict__ xr = (const float4*)(dx + ((size_t)t * BATCH + b) * ISZ);
      #pragma unroll 8
      for (int k = 0; k < ISZ / 4; k++) {
        float4 xv = xr[k]; float4 wv;
        wv = wi0[k]; a0 = fmaf(xv.x, wv.x, fmaf(xv.y, wv.y, fmaf(xv.z, wv.z, fmaf(xv.w, wv.w, a0))));
        wv = wi1[k]; a1 = fmaf(xv.x, wv.x, fmaf(xv.y, wv.y, fmaf(xv.z, wv.z, fmaf(xv.w, wv.w, a1))));
        wv = wi2[k]; a2 = fmaf(xv.x, wv.x, fmaf(xv.y, wv.y, fmaf(xv.z, wv.z, fmaf(xv.w, wv.w, a2))));
        wv = wi3[k]; a3 = fmaf(xv.x, wv.x, fmaf(xv.y, wv.y, fmaf(xv.z, wv.z, fmaf(xv.w, wv.w, a3))));
      }
    }
    {
      #pragma unroll 4
      for (int i = 0; i < 128; ++i) {
        uint4 u = *(const uint4*)(lrow + i * 8);
        float h0 = __half2float(__ushort_as_half((ushort_t)(u.x & 0xffff)));
        float h1 = __half2float(__ushort_as_half((ushort_t)(u.x >> 16)));
        float h2 = __half2float(__ushort_as_half((ushort_t)(u.y & 0xffff)));
        float h3 = __half2float(__ushort_as_half((ushort_t)(u.y >> 16)));
        float h4 = __half2float(__ushort_as_half((ushort_t)(u.z & 0xffff)));
        float h5 = __half2float(__ushort_as_half((ushort_t)(u.z >> 16)));
        float h6 = __half2float(__ushort_as_half((ushort_t)(u.w & 0xffff)));
        float h7 = __half2float(__ushort_as_half((ushort_t)(u.w >> 16)));
        const int wi = i * 2;
        float4 w;
        w = wh0[wi];     a0 = fmaf(h0, w.x, fmaf(h1, w.y, fmaf(h2, w.z, fmaf(h3, w.w, a0))));
        w = wh0[wi + 1]; a0 = fmaf(h4, w.x, fmaf(h5, w.y, fmaf(h6, w.z, fmaf(h7, w.w, a0))));
        w = wh1[wi];     a1 = fmaf(h0, w.x, fmaf(h1, w.y, fmaf(h2, w.z, fmaf(h3, w.w, a1))));
        w = wh1[wi + 1]; a1 = fmaf(h4, w.x, fmaf(h5, w.y, fmaf(h6, w.z, fmaf(h7, w.w, a1))));
        w = wh2[wi];     a2 = fmaf(h0, w.x, fmaf(h1, w.y, fmaf(h2, w.z, fmaf(h3, w.w, a2))));
        w = wh2[wi + 1]; a2 = fmaf(h4, w.x, fmaf(h5, w.y, fmaf(h6, w.z, fmaf(h7, w.w, a2))));
        w = wh3[wi];     a3 = fmaf(h0, w.x, fmaf(h1, w.y, fmaf(h2, w.z, fmaf(h3, w.w, a3))));
        w = wh3[wi + 1]; a3 = fmaf(h4, w.x, fmaf(h5, w.y, fmaf(h6, w.z, fmaf(h7, w.w, a3))));
      }
    }

    m0 += a0; m1 += a1; m2 += a2; m3 += a3;

    float pi = qA(m0), pf = qA(m1), pg = qA(m2), po = qA(m3);
    float gi = qN(sigm(pi));
    float gf = qN(sigm(pf));
    float gg = qN(tanhf(pg));
    float go = qN(sigm(po));
    float cn = c * gf + gi * gg;
    c = qA(cn);
    float ct = qN(tanhf(c));
    h = qA(go * ct);
    out[(size_t)t * (BATCH * HSZ) + (size_t)b * HSZ + j] = h;

    if (t < TSTEPS - 1) {
      float d  = h - hp;
      float da = fabsf(d);
      float dm = (da < TH_QNT) ? 0.0f : d;
      if (da >= TH_RAW) hp = h;
      regacc += fabsf(dm);
      ushort_t my = __half_as_ushort(__float2half(dm));
      ushort_t other = (ushort_t)__shfl((int)my, tid ^ 1, 64);
      if ((tid & 1) == 0) {
        uint_t dw = (uint_t)my | ((uint_t)other << 16);
        uint_t* dhw = (uint_t*)(dh16 + (size_t)((t + 1) & 1) * DHBUF);
        __hip_atomic_store(&dhw[((size_t)b * HSZ + j) >> 1], dw,
                           __ATOMIC_RELAXED, __HIP_MEMORY_SCOPE_AGENT);
      }
    }
    gbar(flags, epoch); epoch++;
  }

  out[OFF_H  + (size_t)b * HSZ + j] = h;
  out[OFF_HP + (size_t)b * HSZ + j] = hp;
  out[OFF_C  + (size_t)b * HSZ + j] = c;
  out[OFF_M  + (size_t)b * GSZ + g0] = m0;
  out[OFF_M  + (size_t)b * GSZ + g1] = m1;
  out[OFF_M  + (size_t)b * GSZ + g2] = m2;
  out[OFF_M  + (size_t)b * GSZ + g3] = m3;

  red[tid] = regacc;
  __syncthreads();
  for (int s = NT / 2; s > 0; s >>= 1) {
    if (tid < s) red[tid] += red[tid + s];
    __syncthreads();
  }
  if (tid == 0)
    __hip_atomic_store(&partials[blockIdx.x], red[0], __ATOMIC_RELAXED, __HIP_MEMORY_SCOPE_AGENT);
  gbar(flags, epoch); epoch++;
  if (blockIdx.x == 0) {
    red[tid] = __hip_atomic_load(&partials[tid], __ATOMIC_RELAXED, __HIP_MEMORY_SCOPE_AGENT);
    __syncthreads();
    for (int s = NT / 2; s > 0; s >>= 1) {
      if (tid < s) red[tid] += red[tid + s];
      __syncthreads();
    }
    if (tid == 0) out[OFF_REG] = red[0];
  }
}

// ---------------------------------------------------------------------------
extern "C" void kernel_launch(void* const* d_in, const int* in_sizes, int n_in,
                              void* d_out, int out_size, void* d_ws, size_t ws_size,
                              hipStream_t stream) {
  const float* x    = (const float*)d_in[0];
  const float* w_ih = (const float*)d_in[1];
  const float* w_hh = (const float*)d_in[2];
  const float* b_ih = (const float*)d_in[3];
  const float* b_hh = (const float*)d_in[4];
  float* out = (float*)d_out;

  const size_t dx_elems = (size_t)TSTEPS * BATCH * ISZ;
  // real-kernel prefix
  float*  dx        = (float*)d_ws;
  __half* dh16      = (__half*)(dx + dx_elems);              // 2*B*H halves
  float*  partials  = (float*)(dh16 + 2 * (size_t)BATCH * HSZ);
  int*    flags     = (int*)(partials + NB);
  size_t needed_real = (size_t)((char*)(flags + NB) - (char*)d_ws);
  if (ws_size < needed_real) return;
  // probe extras (graceful fallback if ws too small)
  __half* dh16p     = (__half*)(flags + NB);
  int*    flagsp    = (int*)(dh16p + 2 * (size_t)BATCH * HSZ);   // 5 regions of NB ints
  float*  dummy     = (float*)(flagsp + 5 * NB);                 // B*H floats
  size_t needed_probe = (size_t)((char*)(dummy + (size_t)BATCH * HSZ) - (char*)d_ws);
  const bool do_probe = (ws_size >= needed_probe);

  (void)hipMemsetAsync(dh16, 0, 2 * (size_t)BATCH * HSZ * sizeof(__half), stream);
  (void)hipMemsetAsync(flags, 0, NB * sizeof(int), stream);
  if (do_probe) {
    (void)hipMemsetAsync(dh16p, 0, 2 * (size_t)BATCH * HSZ * sizeof(__half), stream);
    (void)hipMemsetAsync(flagsp, 0, 5 * NB * sizeof(int), stream);
  }

  xscan_kernel<<<128, 256, 0, stream>>>(x, dx, out + OFF_XPREV);

  if (do_probe) {
    probe_kernel<0, P0STEPS><<<NB, NT, 0, stream>>>(dx, w_ih, w_hh, b_ih, b_hh,
                                                    dummy, dh16p, flagsp + 0 * NB);
    probe_kernel<1, PSTEPS><<<NB, NT, 0, stream>>>(dx, w_ih, w_hh, b_ih, b_hh,
                                                   dummy, dh16p, flagsp + 1 * NB);
    probe_kernel<3, PSTEPS><<<NB, NT, 0, stream>>>(dx, w_ih, w_hh, b_ih, b_hh,
                                                   dummy, dh16p, flagsp + 2 * NB);
    probe_kernel<7, PSTEPS><<<NB, NT, 0, stream>>>(dx, w_ih, w_hh, b_ih, b_hh,
                                                   dummy, dh16p, flagsp + 3 * NB);
    probe_kernel<15, PSTEPS><<<NB, NT, 0, stream>>>(dx, w_ih, w_hh, b_ih, b_hh,
                                                    dummy, dh16p, flagsp + 4 * NB);
  }

  scan_kernel<<<NB, NT, 0, stream>>>(dx, w_ih, w_hh, b_ih, b_hh, out,
                                     dh16, partials, flags);
}